// Round 9
// baseline (151.746 us; speedup 1.0000x reference)
//
#include <hip/hip_runtime.h>
#include <cstdint>
#include <cstddef>

#define DEV __device__ __forceinline__

typedef __bf16 v8bf __attribute__((ext_vector_type(8)));
typedef float v4f __attribute__((ext_vector_type(4)));
typedef float f32x16 __attribute__((ext_vector_type(16)));
typedef uint16_t u16;

DEV u16 f2bf(float f) {
    union { __bf16 b; u16 u; } cv;
    cv.b = (__bf16)f;   // hardware RNE convert
    return cv.u;
}

// pack two f32 -> one u32 of 2 bf16
DEV uint32_t pkbf(float a, float b) {
    typedef __bf16 bf2v __attribute__((ext_vector_type(2)));
    union { bf2v v; uint32_t u; } c;
    c.v = (bf2v){(__bf16)a, (__bf16)b};
    return c.u;
}

// async global -> LDS, 16B per lane; LDS dst is wave-uniform base + lane*16
DEV void gload16(void* lds, const void* g) {
    __builtin_amdgcn_global_load_lds(
        (const __attribute__((address_space(1))) unsigned int*)g,
        (__attribute__((address_space(3))) unsigned int*)lds, 16, 0, 0);
}

DEV void wait_vm0() {
    asm volatile("s_waitcnt vmcnt(0)" ::: "memory");
    __builtin_amdgcn_sched_barrier(0);
}

// ---------------- f32 -> bf16 convert of fc and fs (one launch) ----------------
__global__ __launch_bounds__(256) void k_cvt2(const float* __restrict__ a, const float* __restrict__ b,
                                              u16* __restrict__ da, u16* __restrict__ db) {
    const float* s = blockIdx.y ? b : a;
    u16* d = blockIdx.y ? db : da;
    int i = blockIdx.x * 256 + threadIdx.x;
    float4 v = reinterpret_cast<const float4*>(s)[i];
    ushort4 o;
    o.x = f2bf(v.x); o.y = f2bf(v.y); o.z = f2bf(v.z); o.w = f2bf(v.w);
    reinterpret_cast<ushort4*>(d)[i] = o;
}

// ---------------- weight transpose + convert: Wt[n][k] = bf16(W[k][n]) ----------------
__global__ __launch_bounds__(256) void k_transpose_w(
    const float* __restrict__ w0, const float* __restrict__ w1, const float* __restrict__ w2,
    const float* __restrict__ w3, const float* __restrict__ w4, const float* __restrict__ w5,
    const float* __restrict__ w6, u16* __restrict__ Wt) {
    __shared__ float tl[32][33];
    const float* W;
    switch (blockIdx.z) {
        case 0: W = w0; break; case 1: W = w1; break; case 2: W = w2; break;
        case 3: W = w3; break; case 4: W = w4; break; case 5: W = w5; break;
        default: W = w6; break;
    }
    int n0 = blockIdx.x * 32, k0 = blockIdx.y * 32;
    int tx = threadIdx.x & 31, ty = threadIdx.x >> 5;
    #pragma unroll
    for (int i = 0; i < 4; ++i)
        tl[ty + i*8][tx] = W[(size_t)(k0 + ty + i*8) * 768 + n0 + tx];
    __syncthreads();
    u16* O = Wt + (size_t)blockIdx.z * 589824;
    #pragma unroll
    for (int i = 0; i < 4; ++i)
        O[(size_t)(n0 + ty + i*8) * 768 + k0 + tx] = f2bf(tl[tx][ty + i*8]);
}

// ---------------- bf16 MFMA GEMM core: C[128x128] = A[M,768] * Wt[N,768]^T ----------------
DEV void gemm_main(const u16* __restrict__ A, const u16* __restrict__ W,
                   u16* As, u16* Bs, int m0, int n0, v4f acc[4][4]) {
    const int t = threadIdx.x, lane = t & 63;
    const int wid = t >> 6, wm = wid >> 1, wn = wid & 1;
    const int lr = lane & 15, kg = lane >> 4;
    const int lrow = lane >> 3, lslot = lane & 7;
    const int s = lslot ^ lrow;          // pre-swizzled source slot (row%8 == lrow)
    #pragma unroll
    for (int mi = 0; mi < 4; ++mi)
        #pragma unroll
        for (int ni = 0; ni < 4; ++ni) acc[mi][ni] = (v4f){0.f, 0.f, 0.f, 0.f};
    for (int kt = 0; kt < 12; ++kt) {
        int k0 = kt * 64;
        #pragma unroll
        for (int c = 0; c < 4; ++c) {
            int rb = wid * 32 + c * 8;
            int r = rb + lrow;
            gload16((char*)As + rb * 128, A + (size_t)(m0 + r) * 768 + k0 + s * 8);
            gload16((char*)Bs + rb * 128, W + (size_t)(n0 + r) * 768 + k0 + s * 8);
        }
        __syncthreads();
        #pragma unroll
        for (int kk = 0; kk < 2; ++kk) {
            int kb2 = (kk * 32 + kg * 8) * 2;
            v8bf af[4], bfr[4];
            #pragma unroll
            for (int mi = 0; mi < 4; ++mi) {
                int rr = wm * 64 + mi * 16 + lr;
                af[mi] = *reinterpret_cast<const v8bf*>(reinterpret_cast<const char*>(As) + rr * 128 + (kb2 ^ ((rr & 7) << 4)));
            }
            #pragma unroll
            for (int ni = 0; ni < 4; ++ni) {
                int rr = wn * 64 + ni * 16 + lr;
                bfr[ni] = *reinterpret_cast<const v8bf*>(reinterpret_cast<const char*>(Bs) + rr * 128 + (kb2 ^ ((rr & 7) << 4)));
            }
            #pragma unroll
            for (int mi = 0; mi < 4; ++mi)
                #pragma unroll
                for (int ni = 0; ni < 4; ++ni)
                    acc[mi][ni] = __builtin_amdgcn_mfma_f32_16x16x32_bf16(af[mi], bfr[ni], acc[mi][ni], 0, 0, 0);
        }
        __syncthreads();
    }
}

// 5 projections: z = {qc(*0.125*log2e), kc, vc->vcT (transposed), qs(L2-norm), vs->vsT (transposed)}
__global__ __launch_bounds__(256) void k_gemm_proj(
    const u16* __restrict__ fcb, const u16* __restrict__ fsb, const u16* __restrict__ Wt,
    u16* __restrict__ qc, u16* __restrict__ kc,
    u16* __restrict__ qs, u16* __restrict__ vcT, u16* __restrict__ vsT) {
    __shared__ __align__(16) u16 As[8192], Bs[8192];
    const u16* A; const u16* W; u16* O;
    switch (blockIdx.z) {
        case 0:  A = fcb; W = Wt;              O = qc;  break;
        case 1:  A = fcb; W = Wt + 589824;     O = kc;  break;
        case 2:  A = fcb; W = Wt + 2 * 589824; O = vcT; break;   // transposed epilogue
        case 3:  A = fsb; W = Wt + 3 * 589824; O = qs;  break;
        default: A = fsb; W = Wt + 4 * 589824; O = vsT; break;   // transposed epilogue
    }
    int m0 = blockIdx.y * 128, n0 = blockIdx.x * 128;
    v4f acc[4][4];
    gemm_main(A, W, As, Bs, m0, n0, acc);
    const int lane = threadIdx.x & 63, wid = threadIdx.x >> 6;
    const int wm = wid >> 1, wn = wid & 1, lr = lane & 15, kg = lane >> 4;
    if (blockIdx.z == 0) {
        // fold attention SCALE * log2(e) into qc (softmax uses exp2 directly)
        #pragma unroll
        for (int mi = 0; mi < 4; ++mi)
            #pragma unroll
            for (int ni = 0; ni < 4; ++ni)
                #pragma unroll
                for (int r = 0; r < 4; ++r) acc[mi][ni][r] *= 0.18033688f;
    } else if (blockIdx.z == 3) {
        // fused L2 normalize per 64-col head chunk
        #pragma unroll
        for (int mi = 0; mi < 4; ++mi)
            #pragma unroll
            for (int r = 0; r < 4; ++r) {
                float ss = 0.f;
                #pragma unroll
                for (int ni = 0; ni < 4; ++ni) ss += acc[mi][ni][r] * acc[mi][ni][r];
                ss += __shfl_xor(ss, 1); ss += __shfl_xor(ss, 2);
                ss += __shfl_xor(ss, 4); ss += __shfl_xor(ss, 8);
                float rs = rsqrtf(ss);
                #pragma unroll
                for (int ni = 0; ni < 4; ++ni) acc[mi][ni][r] *= rs;
            }
    }
    if (blockIdx.z == 2 || blockIdx.z == 4) {
        // V projections: write directly transposed vT[(bh*64+d)*1024 + n].
        // Lane's 4 acc rows (r=0..3) are 4 consecutive n -> one aligned ushort4 store.
        #pragma unroll
        for (int mi = 0; mi < 4; ++mi)
            #pragma unroll
            for (int ni = 0; ni < 4; ++ni) {
                int rowg = m0 + wm * 64 + mi * 16 + kg * 4;   // n base (r=0)
                int colg = n0 + wn * 64 + ni * 16 + lr;       // h*64 + d
                int bb = rowg >> 10, nn = rowg & 1023;
                int hh = colg >> 6,  dd = colg & 63;
                ushort4 o;
                o.x = f2bf(acc[mi][ni][0]); o.y = f2bf(acc[mi][ni][1]);
                o.z = f2bf(acc[mi][ni][2]); o.w = f2bf(acc[mi][ni][3]);
                *reinterpret_cast<ushort4*>(O + ((size_t)((bb * 12 + hh) * 64 + dd) * 1024 + nn)) = o;
            }
    } else {
        #pragma unroll
        for (int mi = 0; mi < 4; ++mi)
            #pragma unroll
            for (int ni = 0; ni < 4; ++ni)
                #pragma unroll
                for (int r = 0; r < 4; ++r) {
                    int rowg = m0 + wm * 64 + mi * 16 + kg * 4 + r;
                    int colg = n0 + wn * 64 + ni * 16 + lr;
                    O[(size_t)rowg * 768 + colg] = f2bf(acc[mi][ni][r]);
                }
    }
}

// final 2 projections + bias -> f32 d_out
__global__ __launch_bounds__(256) void k_gemm_out(
    const u16* __restrict__ ocb, const u16* __restrict__ osb, const u16* __restrict__ Wt,
    const float* __restrict__ bpc, const float* __restrict__ bps, float* __restrict__ out) {
    __shared__ __align__(16) u16 As[8192], Bs[8192];
    const u16* A; const u16* W; const float* bias; float* O;
    if (blockIdx.z == 0) { A = ocb; W = Wt + 5 * 589824; bias = bpc; O = out; }
    else                 { A = osb; W = Wt + 6 * 589824; bias = bps; O = out + 3145728; }
    int m0 = blockIdx.y * 128, n0 = blockIdx.x * 128;
    v4f acc[4][4];
    gemm_main(A, W, As, Bs, m0, n0, acc);
    const int lane = threadIdx.x & 63, wid = threadIdx.x >> 6;
    const int wm = wid >> 1, wn = wid & 1, lr = lane & 15, kg = lane >> 4;
    #pragma unroll
    for (int mi = 0; mi < 4; ++mi)
        #pragma unroll
        for (int ni = 0; ni < 4; ++ni)
            #pragma unroll
            for (int r = 0; r < 4; ++r) {
                int rowg = m0 + wm * 64 + mi * 16 + kg * 4 + r;
                int colg = n0 + wn * 64 + ni * 16 + lr;
                O[(size_t)rowg * 768 + colg] = acc[mi][ni][r] + bias[colg];
            }
}

// ---------------- flash attention: 32x32 swapped-QK, P in registers, 48KB LDS ----------------
// (round-7 proven kernel, verbatim)
// K/Q2 single-buffered (read only in QK phase); Vc/Vs double-buffered.
// Two RAW barriers/tile + per-wave counted vmcnt (no full __syncthreads drain).
__global__ __launch_bounds__(256, 2) void k_attn(
    const u16* __restrict__ qc, const u16* __restrict__ kc, const u16* __restrict__ qsn,
    const u16* __restrict__ vcT, const u16* __restrict__ vsT,
    const float* __restrict__ gamma,
    u16* __restrict__ oc, u16* __restrict__ os) {
    __shared__ __align__(16) u16 SH[24576];    // 48KB: K[4096] Q2[4096] Vbuf[2][2][4096]
    u16* K_s8  = SH;
    u16* Q2_s8 = SH + 4096;
    u16* Vb    = SH + 8192;
    const int t = threadIdx.x, lane = t & 63, w = t >> 6;
    const int lq = lane & 31, hf = lane >> 5;
    const int qg = w >> 1, kvh = w & 1;
    const int lrow = lane >> 3, lslot = lane & 7;
    const int sslot = lslot ^ lrow;            // pre-swizzled source slot

    // XCD-chunked swizzle (bijective: 768 = 8 * 96)
    int lin = blockIdx.y * 16 + blockIdx.x;
    int swz = (lin & 7) * 96 + (lin >> 3);
    const int qb = swz & 15, bh = swz >> 4;
    const int b = bh / 12, h = bh % 12;
    const float gam = gamma[h] * 1.44269504088896340736f;

    // per-wave staging source: wave w owns one array
    const u16* gb; size_t rstride, kmul;
    switch (w) {
        case 0:  gb = kc  + (size_t)b * 786432 + h * 64; rstride = 768;  kmul = 768; break;
        case 1:  gb = qsn + (size_t)b * 786432 + h * 64; rstride = 768;  kmul = 768; break;
        case 2:  gb = vcT + (size_t)bh * 65536;          rstride = 1024; kmul = 1;   break;
        default: gb = vsT + (size_t)bh * 65536;          rstride = 1024; kmul = 1;   break;
    }
    u16* fixdst = (w == 0) ? K_s8 : Q2_s8;     // staging dst for w<2 (single-buffered)

    // Q B-fragments in registers: lane holds col q = lq, k-slice = s*16 + hf*8
    const u16* qp1 = qc  + (size_t)(b * 1024 + qb * 64 + qg * 32 + lq) * 768 + h * 64 + hf * 8;
    const u16* qp2 = qsn + (size_t)(b * 1024 + qb * 64 + qg * 32 + lq) * 768 + h * 64 + hf * 8;
    v8bf qcB[4], qsB[4];
    #pragma unroll
    for (int s = 0; s < 4; ++s) {
        qcB[s] = *reinterpret_cast<const v8bf*>(qp1 + s * 16);
        qsB[s] = *reinterpret_cast<const v8bf*>(qp2 + s * 16);
    }

    f32x16 ocA[2], osA[2];
    #pragma unroll
    for (int dt = 0; dt < 2; ++dt) {
        #pragma unroll
        for (int r = 0; r < 16; ++r) { ocA[dt][r] = 0.f; osA[dt][r] = 0.f; }
    }
    float lsum = 0.f;

    // prologue: stage tile 0 (w0->K, w1->Q2, w2->Vc buf0, w3->Vs buf0)
    {
        char* ld = (w < 2) ? (char*)fixdst : (char*)(Vb + (w - 2) * 4096);
        #pragma unroll
        for (int c = 0; c < 8; ++c) {
            int r = c * 8 + lrow;
            gload16(ld + c * 1024, gb + (size_t)r * rstride + sslot * 8);
        }
    }
    wait_vm0();
    __builtin_amdgcn_s_barrier();

    int cur = 0;
    for (int tile = 0; tile < 16; ++tile) {
        // V(t+1) staging issues at top (w2/w3): hidden under the whole tile
        if (tile < 15 && w >= 2) {
            size_t kv1 = (size_t)(tile + 1) * 64;
            char* ld = (char*)(Vb + ((cur ^ 1) * 2 + (w - 2)) * 4096);
            #pragma unroll
            for (int c = 0; c < 8; ++c) {
                int r = c * 8 + lrow;
                gload16(ld + c * 1024, gb + kv1 * kmul + (size_t)r * rstride + sslot * 8);
            }
        }
        const char* K_s  = (const char*)K_s8;
        const char* Q2_s = (const char*)Q2_s8;
        const char* Vc_s = (const char*)(Vb + (cur * 2 + 0) * 4096);
        const char* Vs_s = (const char*)(Vb + (cur * 2 + 1) * 4096);

        // QK: S^T[32 kv][32 q], kv rows = this wave's half
        f32x16 ac, as;
        #pragma unroll
        for (int r = 0; r < 16; ++r) { ac[r] = 0.f; as[r] = 0.f; }
        const int rowA = kvh * 32 + lq;
        __builtin_amdgcn_s_setprio(1);
        #pragma unroll
        for (int s = 0; s < 4; ++s) {
            int colb = s * 32 + hf * 16;   // byte col: d = s*16 + hf*8
            int off = rowA * 128 + (colb ^ ((rowA & 7) << 4));
            v8bf kf  = *reinterpret_cast<const v8bf*>(K_s + off);
            v8bf q2f = *reinterpret_cast<const v8bf*>(Q2_s + off);
            ac = __builtin_amdgcn_mfma_f32_32x32x16_bf16(kf,  qcB[s], ac, 0, 0, 0);
            as = __builtin_amdgcn_mfma_f32_32x32x16_bf16(q2f, qsB[s], as, 0, 0, 0);
        }
        __builtin_amdgcn_s_setprio(0);

        // barrier B: all waves done reading K/Q2(t) -> w0/w1 may overwrite
        __builtin_amdgcn_s_barrier();
        if (tile < 15 && w < 2) {
            size_t kv1 = (size_t)(tile + 1) * 64;
            #pragma unroll
            for (int c = 0; c < 8; ++c) {
                int r = c * 8 + lrow;
                gload16((char*)fixdst + c * 1024, gb + kv1 * kmul + (size_t)r * rstride + sslot * 8);
            }
        }

        // softmax (fixed-shift): p[r] for kv row (r&3)+8*(r>>2)+4*hf, q = lq
        float p[16];
        #pragma unroll
        for (int r = 0; r < 16; ++r)
            p[r] = __builtin_exp2f(fmaf(gam, as[r], ac[r]));
        lsum += ((p[0]+p[1])+(p[2]+p[3])) + ((p[4]+p[5])+(p[6]+p[7]))
              + ((p[8]+p[9])+(p[10]+p[11])) + ((p[12]+p[13])+(p[14]+p[15]));

        // pack P to bf16 A-fragment words (each = 2 consecutive kv)
        uint32_t A0 = pkbf(p[0], p[1]),  A1 = pkbf(p[2], p[3]);
        uint32_t A2 = pkbf(p[4], p[5]),  A3 = pkbf(p[6], p[7]);
        uint32_t A4 = pkbf(p[8], p[9]),  A5 = pkbf(p[10], p[11]);
        uint32_t A6 = pkbf(p[12], p[13]), A7 = pkbf(p[14], p[15]);
        // cross-half exchange, UNCONDITIONAL shfl payloads
        uint32_t pay0 = hf ? A0 : A2;
        uint32_t pay1 = hf ? A1 : A3;
        uint32_t rec0 = (uint32_t)__shfl_xor((int)pay0, 32);
        uint32_t rec1 = (uint32_t)__shfl_xor((int)pay1, 32);
        uint32_t w0 = hf ? rec0 : A0;
        uint32_t w1 = hf ? rec1 : A1;
        uint32_t w2 = hf ? A2 : rec0;
        uint32_t w3 = hf ? A3 : rec1;
        uint32_t pay2 = hf ? A4 : A6;
        uint32_t pay3 = hf ? A5 : A7;
        uint32_t rec2 = (uint32_t)__shfl_xor((int)pay2, 32);
        uint32_t rec3 = (uint32_t)__shfl_xor((int)pay3, 32);
        uint32_t w4 = hf ? rec2 : A4;
        uint32_t w5 = hf ? rec3 : A5;
        uint32_t w6 = hf ? A6 : rec2;
        uint32_t w7 = hf ? A7 : rec3;
        union { uint32_t u[4]; v8bf v; } pa0, pa1;
        pa0.u[0] = w0; pa0.u[1] = w1; pa0.u[2] = w2; pa0.u[3] = w3;
        pa1.u[0] = w4; pa1.u[1] = w5; pa1.u[2] = w6; pa1.u[3] = w7;

        // PV: O[32 q][32 d] per d-tile; A = P-frag, B = V-frag (col d = lq)
        __builtin_amdgcn_s_setprio(1);
        #pragma unroll
        for (int dt = 0; dt < 2; ++dt) {
            int rowV = dt * 32 + lq;
            #pragma unroll
            for (int s = 0; s < 2; ++s) {
                int colb = kvh * 64 + s * 32 + hf * 16;  // byte col: kv = kvh*32+s*16+hf*8
                int off = rowV * 128 + (colb ^ ((rowV & 7) << 4));
                v8bf vcf = *reinterpret_cast<const v8bf*>(Vc_s + off);
                v8bf vsf = *reinterpret_cast<const v8bf*>(Vs_s + off);
                v8bf ap = s ? pa1.v : pa0.v;
                ocA[dt] = __builtin_amdgcn_mfma_f32_32x32x16_bf16(ap, vcf, ocA[dt], 0, 0, 0);
                osA[dt] = __builtin_amdgcn_mfma_f32_32x32x16_bf16(ap, vsf, osA[dt], 0, 0, 0);
            }
        }
        __builtin_amdgcn_s_setprio(0);

        // wait own staging loads, then barrier A
        wait_vm0();
        __builtin_amdgcn_s_barrier();
        cur ^= 1;
    }

    // ---- epilogue: cross-kv-half reduction via LDS ----
    lsum += __shfl_xor(lsum, 32);
    float* red   = reinterpret_cast<float*>(SH);
    float* red_l = red;                  // [2 qg][32 q]
    float* red_o = red + 64;             // [2 qg][64 idx][64 lane]
    if (kvh == 1) {
        if (lane < 32) red_l[qg * 32 + lq] = lsum;
        #pragma unroll
        for (int st = 0; st < 2; ++st)
            #pragma unroll
            for (int dt = 0; dt < 2; ++dt)
                #pragma unroll
                for (int r = 0; r < 16; ++r) {
                    int idx = st * 32 + dt * 16 + r;
                    float v = st ? osA[dt][r] : ocA[dt][r];
                    red_o[(qg * 64 + idx) * 64 + lane] = v;
                }
    }
    __syncthreads();
    if (kvh == 0) {
        float ltot = lsum + red_l[qg * 32 + lq];
        float rl = 1.0f / ltot;
        if (lane < 32) red_l[qg * 32 + lq] = rl;
        #pragma unroll
        for (int st = 0; st < 2; ++st)
            #pragma unroll
            for (int dt = 0; dt < 2; ++dt)
                #pragma unroll
                for (int r = 0; r < 16; ++r) {
                    int rowq = (r & 3) + 8 * (r >> 2) + 4 * hf;
                    float rlv = red_l[qg * 32 + rowq];
                    int idx = st * 32 + dt * 16 + r;
                    float own = st ? osA[dt][r] : ocA[dt][r];
                    float v = (own + red_o[(qg * 64 + idx) * 64 + lane]) * rlv;
                    u16* dst = st ? os : oc;
                    dst[(size_t)(b * 1024 + qb * 64 + qg * 32 + rowq) * 768 + h * 64 + dt * 32 + lq] = f2bf(v);
                }
    }
}

extern "C" void kernel_launch(void* const* d_in, const int* in_sizes, int n_in,
                              void* d_out, int out_size, void* d_ws, size_t ws_size,
                              hipStream_t stream) {
    const float* fc    = (const float*)d_in[0];
    const float* fs    = (const float*)d_in[1];
    const float* Wqc   = (const float*)d_in[2];
    const float* Wqs   = (const float*)d_in[3];
    const float* Wkc   = (const float*)d_in[4];
    const float* Wvc   = (const float*)d_in[5];
    const float* Wvs   = (const float*)d_in[6];
    const float* gamma = (const float*)d_in[7];
    const float* Wpc   = (const float*)d_in[8];
    const float* bpc   = (const float*)d_in[9];
    const float* Wps   = (const float*)d_in[10];
    const float* bps   = (const float*)d_in[11];
    float* out = (float*)d_out;

    const size_t NT = 3145728;  // 4096*768 elements
    u16* ws  = (u16*)d_ws;
    u16* fcb = ws;
    u16* fsb = fcb + NT;
    u16* Wt  = fsb + NT;            // 7 * 589824
    u16* qc  = Wt + (size_t)7 * 589824;
    u16* kc  = qc + NT;
    u16* vc  = kc + NT;             // unused (kept for layout stability)
    u16* qs  = vc + NT;
    u16* vs  = qs + NT;             // unused
    u16* vcT = vs + NT;
    u16* vsT = vcT + NT;
    u16* ocb = fcb;  // fcb/fsb dead after projections -> reuse for attention outputs
    u16* osb = fsb;

    k_cvt2<<<dim3(3072, 2), 256, 0, stream>>>(fc, fs, fcb, fsb);
    k_transpose_w<<<dim3(24, 24, 7), 256, 0, stream>>>(Wqc, Wkc, Wvc, Wqs, Wvs, Wpc, Wps, Wt);
    k_gemm_proj<<<dim3(6, 32, 5), 256, 0, stream>>>(fcb, fsb, Wt, qc, kc, qs, vcT, vsT);
    k_attn<<<dim3(16, 48), 256, 0, stream>>>(qc, kc, qs, vcT, vsT, gamma, ocb, osb);
    k_gemm_out<<<dim3(6, 32, 2), 256, 0, stream>>>(ocb, osb, Wt, bpc, bps, out);
}

// Round 11
// 132.228 us; speedup vs baseline: 1.1476x; 1.1476x over previous
//
#include <hip/hip_runtime.h>
#include <cstdint>
#include <cstddef>

#define DEV __device__ __forceinline__

typedef __bf16 v8bf __attribute__((ext_vector_type(8)));
typedef float v4f __attribute__((ext_vector_type(4)));
typedef float f32x16 __attribute__((ext_vector_type(16)));
typedef uint16_t u16;

DEV u16 f2bf(float f) {
    union { __bf16 b; u16 u; } cv;
    cv.b = (__bf16)f;   // hardware RNE convert
    return cv.u;
}

// pack two f32 -> one u32 of 2 bf16
DEV uint32_t pkbf(float a, float b) {
    typedef __bf16 bf2v __attribute__((ext_vector_type(2)));
    union { bf2v v; uint32_t u; } c;
    c.v = (bf2v){(__bf16)a, (__bf16)b};
    return c.u;
}

// async global -> LDS, 16B per lane; LDS dst is wave-uniform base + lane*16
DEV void gload16(void* lds, const void* g) {
    __builtin_amdgcn_global_load_lds(
        (const __attribute__((address_space(1))) unsigned int*)g,
        (__attribute__((address_space(3))) unsigned int*)lds, 16, 0, 0);
}

// ---------------- prep: f32->bf16 convert of fc/fs + weight transposes, one launch ----------------
// BUGFIX (round 10): was `bid & 3071` — 3072 is NOT a power of two; &3071 clears bit 10,
// aliasing blocks [1024,2048) onto [0,1024) and leaving fcb/fsb rows unwritten.
__global__ __launch_bounds__(256) void k_prep(
    const float* __restrict__ fc, const float* __restrict__ fs,
    u16* __restrict__ fcb, u16* __restrict__ fsb,
    const float* __restrict__ w0, const float* __restrict__ w1, const float* __restrict__ w2,
    const float* __restrict__ w3, const float* __restrict__ w4, const float* __restrict__ w5,
    const float* __restrict__ w6, u16* __restrict__ Wt) {
    __shared__ float tl[32][33];
    int bid = blockIdx.x;
    if (bid < 6144) {
        const float* s = (bid < 3072) ? fc : fs;
        u16* d = (bid < 3072) ? fcb : fsb;
        int blk = (bid < 3072) ? bid : (bid - 3072);   // exact, not a mask
        int i = blk * 256 + threadIdx.x;
        float4 v = reinterpret_cast<const float4*>(s)[i];
        ushort4 o;
        o.x = f2bf(v.x); o.y = f2bf(v.y); o.z = f2bf(v.z); o.w = f2bf(v.w);
        reinterpret_cast<ushort4*>(d)[i] = o;
        return;
    }
    int tid = bid - 6144;          // 0..4031
    int z = tid / 576, rem = tid % 576;
    const float* W;
    switch (z) {
        case 0: W = w0; break; case 1: W = w1; break; case 2: W = w2; break;
        case 3: W = w3; break; case 4: W = w4; break; case 5: W = w5; break;
        default: W = w6; break;
    }
    int n0 = (rem % 24) * 32, k0 = (rem / 24) * 32;
    int tx = threadIdx.x & 31, ty = threadIdx.x >> 5;
    #pragma unroll
    for (int i = 0; i < 4; ++i)
        tl[ty + i*8][tx] = W[(size_t)(k0 + ty + i*8) * 768 + n0 + tx];
    __syncthreads();
    u16* O = Wt + (size_t)z * 589824;
    #pragma unroll
    for (int i = 0; i < 4; ++i)
        O[(size_t)(n0 + ty + i*8) * 768 + k0 + tx] = f2bf(tl[tx][ty + i*8]);
}

// ---------------- bf16 MFMA GEMM core: C[128x128] = A[M,768] * Wt[N,768]^T ----------------
DEV void gemm_main(const u16* __restrict__ A, const u16* __restrict__ W,
                   u16* As, u16* Bs, int m0, int n0, v4f acc[4][4]) {
    const int t = threadIdx.x, lane = t & 63;
    const int wid = t >> 6, wm = wid >> 1, wn = wid & 1;
    const int lr = lane & 15, kg = lane >> 4;
    const int lrow = lane >> 3, lslot = lane & 7;
    const int s = lslot ^ lrow;          // pre-swizzled source slot (row%8 == lrow)
    #pragma unroll
    for (int mi = 0; mi < 4; ++mi)
        #pragma unroll
        for (int ni = 0; ni < 4; ++ni) acc[mi][ni] = (v4f){0.f, 0.f, 0.f, 0.f};
    for (int kt = 0; kt < 12; ++kt) {
        int k0 = kt * 64;
        #pragma unroll
        for (int c = 0; c < 4; ++c) {
            int rb = wid * 32 + c * 8;
            int r = rb + lrow;
            gload16((char*)As + rb * 128, A + (size_t)(m0 + r) * 768 + k0 + s * 8);
            gload16((char*)Bs + rb * 128, W + (size_t)(n0 + r) * 768 + k0 + s * 8);
        }
        __syncthreads();
        #pragma unroll
        for (int kk = 0; kk < 2; ++kk) {
            int kb2 = (kk * 32 + kg * 8) * 2;
            v8bf af[4], bfr[4];
            #pragma unroll
            for (int mi = 0; mi < 4; ++mi) {
                int rr = wm * 64 + mi * 16 + lr;
                af[mi] = *reinterpret_cast<const v8bf*>(reinterpret_cast<const char*>(As) + rr * 128 + (kb2 ^ ((rr & 7) << 4)));
            }
            #pragma unroll
            for (int ni = 0; ni < 4; ++ni) {
                int rr = wn * 64 + ni * 16 + lr;
                bfr[ni] = *reinterpret_cast<const v8bf*>(reinterpret_cast<const char*>(Bs) + rr * 128 + (kb2 ^ ((rr & 7) << 4)));
            }
            #pragma unroll
            for (int mi = 0; mi < 4; ++mi)
                #pragma unroll
                for (int ni = 0; ni < 4; ++ni)
                    acc[mi][ni] = __builtin_amdgcn_mfma_f32_16x16x32_bf16(af[mi], bfr[ni], acc[mi][ni], 0, 0, 0);
        }
        __syncthreads();
    }
}

// 5 projections: z = {qc(*0.125*log2e), kc, vc, qs(L2-normalized), vs} — coalesced epilogue
__global__ __launch_bounds__(256) void k_gemm_proj(
    const u16* __restrict__ fcb, const u16* __restrict__ fsb, const u16* __restrict__ Wt,
    u16* __restrict__ qc, u16* __restrict__ kc, u16* __restrict__ vc,
    u16* __restrict__ qs, u16* __restrict__ vs) {
    __shared__ __align__(16) u16 As[8192], Bs[8192];
    const u16* A; const u16* W; u16* O;
    switch (blockIdx.z) {
        case 0:  A = fcb; W = Wt;              O = qc; break;
        case 1:  A = fcb; W = Wt + 589824;     O = kc; break;
        case 2:  A = fcb; W = Wt + 2 * 589824; O = vc; break;
        case 3:  A = fsb; W = Wt + 3 * 589824; O = qs; break;
        default: A = fsb; W = Wt + 4 * 589824; O = vs; break;
    }
    int m0 = blockIdx.y * 128, n0 = blockIdx.x * 128;
    v4f acc[4][4];
    gemm_main(A, W, As, Bs, m0, n0, acc);
    const int lane = threadIdx.x & 63, wid = threadIdx.x >> 6;
    const int wm = wid >> 1, wn = wid & 1, lr = lane & 15, kg = lane >> 4;
    if (blockIdx.z == 0) {
        #pragma unroll
        for (int mi = 0; mi < 4; ++mi)
            #pragma unroll
            for (int ni = 0; ni < 4; ++ni)
                #pragma unroll
                for (int r = 0; r < 4; ++r) acc[mi][ni][r] *= 0.18033688f;
    } else if (blockIdx.z == 3) {
        #pragma unroll
        for (int mi = 0; mi < 4; ++mi)
            #pragma unroll
            for (int r = 0; r < 4; ++r) {
                float ss = 0.f;
                #pragma unroll
                for (int ni = 0; ni < 4; ++ni) ss += acc[mi][ni][r] * acc[mi][ni][r];
                ss += __shfl_xor(ss, 1); ss += __shfl_xor(ss, 2);
                ss += __shfl_xor(ss, 4); ss += __shfl_xor(ss, 8);
                float rs = rsqrtf(ss);
                #pragma unroll
                for (int ni = 0; ni < 4; ++ni) acc[mi][ni][r] *= rs;
            }
    }
    #pragma unroll
    for (int mi = 0; mi < 4; ++mi)
        #pragma unroll
        for (int ni = 0; ni < 4; ++ni)
            #pragma unroll
            for (int r = 0; r < 4; ++r) {
                int rowg = m0 + wm * 64 + mi * 16 + kg * 4 + r;
                int colg = n0 + wn * 64 + ni * 16 + lr;
                O[(size_t)rowg * 768 + colg] = f2bf(acc[mi][ni][r]);
            }
}

// final 2 projections + bias -> f32 d_out
__global__ __launch_bounds__(256) void k_gemm_out(
    const u16* __restrict__ ocb, const u16* __restrict__ osb, const u16* __restrict__ Wt,
    const float* __restrict__ bpc, const float* __restrict__ bps, float* __restrict__ out) {
    __shared__ __align__(16) u16 As[8192], Bs[8192];
    const u16* A; const u16* W; const float* bias; float* O;
    if (blockIdx.z == 0) { A = ocb; W = Wt + 5 * 589824; bias = bpc; O = out; }
    else                 { A = osb; W = Wt + 6 * 589824; bias = bps; O = out + 3145728; }
    int m0 = blockIdx.y * 128, n0 = blockIdx.x * 128;
    v4f acc[4][4];
    gemm_main(A, W, As, Bs, m0, n0, acc);
    const int lane = threadIdx.x & 63, wid = threadIdx.x >> 6;
    const int wm = wid >> 1, wn = wid & 1, lr = lane & 15, kg = lane >> 4;
    #pragma unroll
    for (int mi = 0; mi < 4; ++mi)
        #pragma unroll
        for (int ni = 0; ni < 4; ++ni)
            #pragma unroll
            for (int r = 0; r < 4; ++r) {
                int rowg = m0 + wm * 64 + mi * 16 + kg * 4 + r;
                int colg = n0 + wn * 64 + ni * 16 + lr;
                O[(size_t)rowg * 768 + colg] = acc[mi][ni][r] + bias[colg];
            }
}

// ---------------- V transpose: vT[(bh*64+d)*1024 + n] = v[(b*1024+n)*768 + h*64 + d] ----------------
__global__ __launch_bounds__(256) void k_transpose_v(
    const u16* __restrict__ vc, const u16* __restrict__ vs,
    u16* __restrict__ vcT, u16* __restrict__ vsT) {
    __shared__ u16 tile[64][65];
    const u16* src = blockIdx.z ? vs : vc;
    u16* dst = blockIdx.z ? vsT : vcT;
    int bh = blockIdx.y, b = bh / 12, h = bh % 12;
    int n0 = blockIdx.x * 64;
    int t = threadIdx.x;
    #pragma unroll
    for (int i = 0; i < 16; ++i) {
        int idx = i * 256 + t, n = idx >> 6, d = idx & 63;
        tile[n][d] = src[(size_t)(b * 1024 + n0 + n) * 768 + h * 64 + d];
    }
    __syncthreads();
    #pragma unroll
    for (int i = 0; i < 16; ++i) {
        int idx = i * 256 + t, d = idx >> 6, n = idx & 63;
        dst[(size_t)(bh * 64 + d) * 1024 + n0 + n] = tile[n][d];
    }
}

// ---------------- flash attention: 8 waves, 128 q-rows/block, 32x32 swapped-QK, P in registers ----------------
// All four arrays double-buffered (64KB), ONE __syncthreads per tile (full fence+drain;
// staging issued at tile top still hides under the tile's compute).
// 8 waves = 4 q-groups x 2 kv-halves; each wave stages half of one array.
// Grid 384 x 512thr: 2 blocks/CU -> all co-resident, 4 waves/SIMD.
__global__ __launch_bounds__(512, 2) void k_attn(
    const u16* __restrict__ qc, const u16* __restrict__ kc, const u16* __restrict__ qsn,
    const u16* __restrict__ vcT, const u16* __restrict__ vsT,
    const float* __restrict__ gamma,
    u16* __restrict__ oc, u16* __restrict__ os) {
    __shared__ __align__(16) u16 KQ[2][4][4096];   // [buf][K|Q2|Vc|Vs][64 x 64] = 64KB
    const int t = threadIdx.x, lane = t & 63, w = t >> 6;  // w 0..7
    const int lq = lane & 31, hf = lane >> 5;
    const int qg = w >> 1, kvh = w & 1;        // compute role
    const int arr = w >> 1, half = w & 1;      // staging role: half of array arr
    const int lrow = lane >> 3, lslot = lane & 7;
    const int sslot = lslot ^ lrow;            // pre-swizzled source slot

    // XCD-chunked swizzle (bijective: 384 = 8 * 48)
    int lin = blockIdx.y * 8 + blockIdx.x;
    int swz = (lin & 7) * 48 + (lin >> 3);
    const int qb = swz & 7, bh = swz >> 3;
    const int b = bh / 12, h = bh % 12;
    const float gam = gamma[h] * 1.44269504088896340736f;

    // staging source for this wave's array
    const u16* gb; size_t rstride, kmul;
    switch (arr) {
        case 0:  gb = kc  + (size_t)b * 786432 + h * 64; rstride = 768;  kmul = 768; break;
        case 1:  gb = qsn + (size_t)b * 786432 + h * 64; rstride = 768;  kmul = 768; break;
        case 2:  gb = vcT + (size_t)bh * 65536;          rstride = 1024; kmul = 1;   break;
        default: gb = vsT + (size_t)bh * 65536;          rstride = 1024; kmul = 1;   break;
    }

    // Q B-fragments: lane holds col q = lq of its q-group, k-slice = s*16 + hf*8
    const u16* qp1 = qc  + (size_t)(b * 1024 + qb * 128 + qg * 32 + lq) * 768 + h * 64 + hf * 8;
    const u16* qp2 = qsn + (size_t)(b * 1024 + qb * 128 + qg * 32 + lq) * 768 + h * 64 + hf * 8;
    v8bf qcB[4], qsB[4];
    #pragma unroll
    for (int s = 0; s < 4; ++s) {
        qcB[s] = *reinterpret_cast<const v8bf*>(qp1 + s * 16);
        qsB[s] = *reinterpret_cast<const v8bf*>(qp2 + s * 16);
    }

    f32x16 ocA[2], osA[2];
    #pragma unroll
    for (int dt = 0; dt < 2; ++dt) {
        #pragma unroll
        for (int r = 0; r < 16; ++r) { ocA[dt][r] = 0.f; osA[dt][r] = 0.f; }
    }
    float lsum = 0.f;

    // prologue: stage tile 0 into buf 0 (wave w -> half `half` of array `arr`)
    {
        char* ld = (char*)KQ[0][arr] + half * 4096;
        #pragma unroll
        for (int c = 0; c < 4; ++c) {
            int r = half * 32 + c * 8 + lrow;
            gload16(ld + c * 1024, gb + (size_t)r * rstride + sslot * 8);
        }
    }
    __syncthreads();

    int cur = 0;
    for (int tile = 0; tile < 16; ++tile) {
        // issue next tile's staging into buf^1 (flies under this tile's compute)
        if (tile < 15) {
            size_t kv1 = (size_t)(tile + 1) * 64;
            char* ld = (char*)KQ[cur ^ 1][arr] + half * 4096;
            #pragma unroll
            for (int c = 0; c < 4; ++c) {
                int r = half * 32 + c * 8 + lrow;
                gload16(ld + c * 1024, gb + kv1 * kmul + (size_t)r * rstride + sslot * 8);
            }
        }
        const char* K_s  = (const char*)KQ[cur][0];
        const char* Q2_s = (const char*)KQ[cur][1];
        const char* Vc_s = (const char*)KQ[cur][2];
        const char* Vs_s = (const char*)KQ[cur][3];

        // QK: S^T[32 kv][32 q], kv rows = this wave's half
        f32x16 ac, as;
        #pragma unroll
        for (int r = 0; r < 16; ++r) { ac[r] = 0.f; as[r] = 0.f; }
        const int rowA = kvh * 32 + lq;
        __builtin_amdgcn_s_setprio(1);
        #pragma unroll
        for (int s = 0; s < 4; ++s) {
            int colb = s * 32 + hf * 16;   // byte col: d = s*16 + hf*8
            int off = rowA * 128 + (colb ^ ((rowA & 7) << 4));
            v8bf kf  = *reinterpret_cast<const v8bf*>(K_s + off);
            v8bf q2f = *reinterpret_cast<const v8bf*>(Q2_s + off);
            ac = __builtin_amdgcn_mfma_f32_32x32x16_bf16(kf,  qcB[s], ac, 0, 0, 0);
            as = __builtin_amdgcn_mfma_f32_32x32x16_bf16(q2f, qsB[s], as, 0, 0, 0);
        }
        __builtin_amdgcn_s_setprio(0);

        // softmax (fixed-shift): p[r] for kv row (r&3)+8*(r>>2)+4*hf, q = lq
        float p[16];
        #pragma unroll
        for (int r = 0; r < 16; ++r)
            p[r] = __builtin_exp2f(fmaf(gam, as[r], ac[r]));
        lsum += ((p[0]+p[1])+(p[2]+p[3])) + ((p[4]+p[5])+(p[6]+p[7]))
              + ((p[8]+p[9])+(p[10]+p[11])) + ((p[12]+p[13])+(p[14]+p[15]));

        // pack P to bf16 A-fragment words (each = 2 consecutive kv)
        uint32_t A0 = pkbf(p[0], p[1]),  A1 = pkbf(p[2], p[3]);
        uint32_t A2 = pkbf(p[4], p[5]),  A3 = pkbf(p[6], p[7]);
        uint32_t A4 = pkbf(p[8], p[9]),  A5 = pkbf(p[10], p[11]);
        uint32_t A6 = pkbf(p[12], p[13]), A7 = pkbf(p[14], p[15]);
        // cross-half exchange, UNCONDITIONAL shfl payloads
        uint32_t pay0 = hf ? A0 : A2;
        uint32_t pay1 = hf ? A1 : A3;
        uint32_t rec0 = (uint32_t)__shfl_xor((int)pay0, 32);
        uint32_t rec1 = (uint32_t)__shfl_xor((int)pay1, 32);
        uint32_t w0 = hf ? rec0 : A0;
        uint32_t w1 = hf ? rec1 : A1;
        uint32_t w2 = hf ? A2 : rec0;
        uint32_t w3 = hf ? A3 : rec1;
        uint32_t pay2 = hf ? A4 : A6;
        uint32_t pay3 = hf ? A5 : A7;
        uint32_t rec2 = (uint32_t)__shfl_xor((int)pay2, 32);
        uint32_t rec3 = (uint32_t)__shfl_xor((int)pay3, 32);
        uint32_t w4 = hf ? rec2 : A4;
        uint32_t w5 = hf ? rec3 : A5;
        uint32_t w6 = hf ? A6 : rec2;
        uint32_t w7 = hf ? A7 : rec3;
        union { uint32_t u[4]; v8bf v; } pa0, pa1;
        pa0.u[0] = w0; pa0.u[1] = w1; pa0.u[2] = w2; pa0.u[3] = w3;
        pa1.u[0] = w4; pa1.u[1] = w5; pa1.u[2] = w6; pa1.u[3] = w7;

        // PV: O[32 q][32 d] per d-tile; A = P-frag, B = V-frag (col d = lq)
        __builtin_amdgcn_s_setprio(1);
        #pragma unroll
        for (int dt = 0; dt < 2; ++dt) {
            int rowV = dt * 32 + lq;
            #pragma unroll
            for (int s = 0; s < 2; ++s) {
                int colb = kvh * 64 + s * 32 + hf * 16;  // byte col: kv = kvh*32+s*16+hf*8
                int off = rowV * 128 + (colb ^ ((rowV & 7) << 4));
                v8bf vcf = *reinterpret_cast<const v8bf*>(Vc_s + off);
                v8bf vsf = *reinterpret_cast<const v8bf*>(Vs_s + off);
                v8bf ap = s ? pa1.v : pa0.v;
                ocA[dt] = __builtin_amdgcn_mfma_f32_32x32x16_bf16(ap, vcf, ocA[dt], 0, 0, 0);
                osA[dt] = __builtin_amdgcn_mfma_f32_32x32x16_bf16(ap, vsf, osA[dt], 0, 0, 0);
            }
        }
        __builtin_amdgcn_s_setprio(0);

        __syncthreads();   // full fence+drain: next-tile staging landed, buf swap safe
        cur ^= 1;
    }

    // ---- epilogue: cross-kv-half reduction via LDS, two passes (oc then os) ----
    lsum += __shfl_xor(lsum, 32);
    float* red   = reinterpret_cast<float*>(&KQ[0][0][0]);
    float* red_l = red;                  // [4 qg][32 q]
    float* red_o = red + 128;            // [4 qg][32 idx][64 lane] = 32KB
    if (kvh == 1) {
        if (lane < 32) red_l[qg * 32 + lq] = lsum;
        #pragma unroll
        for (int dt = 0; dt < 2; ++dt)
            #pragma unroll
            for (int r = 0; r < 16; ++r)
                red_o[(qg * 32 + dt * 16 + r) * 64 + lane] = ocA[dt][r];
    }
    __syncthreads();
    if (kvh == 0) {
        float ltot = lsum + red_l[qg * 32 + lq];
        float rl = 1.0f / ltot;
        if (lane < 32) red_l[qg * 32 + lq] = rl;
        #pragma unroll
        for (int dt = 0; dt < 2; ++dt)
            #pragma unroll
            for (int r = 0; r < 16; ++r) {
                int rowq = (r & 3) + 8 * (r >> 2) + 4 * hf;
                float rlv = red_l[qg * 32 + rowq];
                float v = (ocA[dt][r] + red_o[(qg * 32 + dt * 16 + r) * 64 + lane]) * rlv;
                oc[(size_t)(b * 1024 + qb * 128 + qg * 32 + rowq) * 768 + h * 64 + dt * 32 + lq] = f2bf(v);
            }
    }
    __syncthreads();
    if (kvh == 1) {
        #pragma unroll
        for (int dt = 0; dt < 2; ++dt)
            #pragma unroll
            for (int r = 0; r < 16; ++r)
                red_o[(qg * 32 + dt * 16 + r) * 64 + lane] = osA[dt][r];
    }
    __syncthreads();
    if (kvh == 0) {
        #pragma unroll
        for (int dt = 0; dt < 2; ++dt)
            #pragma unroll
            for (int r = 0; r < 16; ++r) {
                int rowq = (r & 3) + 8 * (r >> 2) + 4 * hf;
                float rlv = red_l[qg * 32 + rowq];
                float v = (osA[dt][r] + red_o[(qg * 32 + dt * 16 + r) * 64 + lane]) * rlv;
                os[(size_t)(b * 1024 + qb * 128 + qg * 32 + rowq) * 768 + h * 64 + dt * 32 + lq] = f2bf(v);
            }
    }
}

extern "C" void kernel_launch(void* const* d_in, const int* in_sizes, int n_in,
                              void* d_out, int out_size, void* d_ws, size_t ws_size,
                              hipStream_t stream) {
    const float* fc    = (const float*)d_in[0];
    const float* fs    = (const float*)d_in[1];
    const float* Wqc   = (const float*)d_in[2];
    const float* Wqs   = (const float*)d_in[3];
    const float* Wkc   = (const float*)d_in[4];
    const float* Wvc   = (const float*)d_in[5];
    const float* Wvs   = (const float*)d_in[6];
    const float* gamma = (const float*)d_in[7];
    const float* Wpc   = (const float*)d_in[8];
    const float* bpc   = (const float*)d_in[9];
    const float* Wps   = (const float*)d_in[10];
    const float* bps   = (const float*)d_in[11];
    float* out = (float*)d_out;

    const size_t NT = 3145728;  // 4096*768 elements
    u16* ws  = (u16*)d_ws;
    u16* fcb = ws;
    u16* fsb = fcb + NT;
    u16* Wt  = fsb + NT;            // 7 * 589824
    u16* qc  = Wt + (size_t)7 * 589824;
    u16* kc  = qc + NT;
    u16* vc  = kc + NT;
    u16* qs  = vc + NT;
    u16* vs  = qs + NT;
    u16* vcT = vs + NT;
    u16* vsT = vcT + NT;
    u16* ocb = fcb;  // fcb/fsb dead after projections -> reuse for attention outputs
    u16* osb = fsb;

    k_prep<<<10176, 256, 0, stream>>>(fc, fs, fcb, fsb, Wqc, Wkc, Wvc, Wqs, Wvs, Wpc, Wps, Wt);
    k_gemm_proj<<<dim3(6, 32, 5), 256, 0, stream>>>(fcb, fsb, Wt, qc, kc, vc, qs, vs);
    k_transpose_v<<<dim3(16, 48, 2), 256, 0, stream>>>(vc, vs, vcT, vsT);
    k_attn<<<dim3(8, 48), 512, 0, stream>>>(qc, kc, qs, vcT, vsT, gamma, ocb, osb);
    k_gemm_out<<<dim3(6, 32, 2), 256, 0, stream>>>(ocb, osb, Wt, bpc, bps, out);
}

// Round 12
// 124.991 us; speedup vs baseline: 1.2141x; 1.0579x over previous
//
#include <hip/hip_runtime.h>
#include <cstdint>
#include <cstddef>

#define DEV __device__ __forceinline__

typedef __bf16 v8bf __attribute__((ext_vector_type(8)));
typedef float v4f __attribute__((ext_vector_type(4)));
typedef float f32x16 __attribute__((ext_vector_type(16)));
typedef uint16_t u16;

DEV u16 f2bf(float f) {
    union { __bf16 b; u16 u; } cv;
    cv.b = (__bf16)f;   // hardware RNE convert
    return cv.u;
}

// pack two f32 -> one u32 of 2 bf16
DEV uint32_t pkbf(float a, float b) {
    typedef __bf16 bf2v __attribute__((ext_vector_type(2)));
    union { bf2v v; uint32_t u; } c;
    c.v = (bf2v){(__bf16)a, (__bf16)b};
    return c.u;
}

// async global -> LDS, 16B per lane; LDS dst is wave-uniform base + lane*16
DEV void gload16(void* lds, const void* g) {
    __builtin_amdgcn_global_load_lds(
        (const __attribute__((address_space(1))) unsigned int*)g,
        (__attribute__((address_space(3))) unsigned int*)lds, 16, 0, 0);
}

DEV void wait_vm0() {
    asm volatile("s_waitcnt vmcnt(0)" ::: "memory");
    __builtin_amdgcn_sched_barrier(0);
}

// ---------------- prep: f32->bf16 convert of fc/fs + weight transposes, one launch ----------------
__global__ __launch_bounds__(256) void k_prep(
    const float* __restrict__ fc, const float* __restrict__ fs,
    u16* __restrict__ fcb, u16* __restrict__ fsb,
    const float* __restrict__ w0, const float* __restrict__ w1, const float* __restrict__ w2,
    const float* __restrict__ w3, const float* __restrict__ w4, const float* __restrict__ w5,
    const float* __restrict__ w6, u16* __restrict__ Wt) {
    __shared__ float tl[32][33];
    int bid = blockIdx.x;
    if (bid < 6144) {
        const float* s = (bid < 3072) ? fc : fs;
        u16* d = (bid < 3072) ? fcb : fsb;
        int blk = (bid < 3072) ? bid : (bid - 3072);   // exact, not a mask (3072 != pow2)
        int i = blk * 256 + threadIdx.x;
        float4 v = reinterpret_cast<const float4*>(s)[i];
        ushort4 o;
        o.x = f2bf(v.x); o.y = f2bf(v.y); o.z = f2bf(v.z); o.w = f2bf(v.w);
        reinterpret_cast<ushort4*>(d)[i] = o;
        return;
    }
    int tid = bid - 6144;          // 0..4031
    int z = tid / 576, rem = tid % 576;
    const float* W;
    switch (z) {
        case 0: W = w0; break; case 1: W = w1; break; case 2: W = w2; break;
        case 3: W = w3; break; case 4: W = w4; break; case 5: W = w5; break;
        default: W = w6; break;
    }
    int n0 = (rem % 24) * 32, k0 = (rem / 24) * 32;
    int tx = threadIdx.x & 31, ty = threadIdx.x >> 5;
    #pragma unroll
    for (int i = 0; i < 4; ++i)
        tl[ty + i*8][tx] = W[(size_t)(k0 + ty + i*8) * 768 + n0 + tx];
    __syncthreads();
    u16* O = Wt + (size_t)z * 589824;
    #pragma unroll
    for (int i = 0; i < 4; ++i)
        O[(size_t)(n0 + ty + i*8) * 768 + k0 + tx] = f2bf(tl[tx][ty + i*8]);
}

// ---------------- bf16 MFMA GEMM core: C[128x128] = A[M,768] * Wt[N,768]^T ----------------
DEV void gemm_main(const u16* __restrict__ A, const u16* __restrict__ W,
                   u16* As, u16* Bs, int m0, int n0, v4f acc[4][4]) {
    const int t = threadIdx.x, lane = t & 63;
    const int wid = t >> 6, wm = wid >> 1, wn = wid & 1;
    const int lr = lane & 15, kg = lane >> 4;
    const int lrow = lane >> 3, lslot = lane & 7;
    const int s = lslot ^ lrow;          // pre-swizzled source slot (row%8 == lrow)
    #pragma unroll
    for (int mi = 0; mi < 4; ++mi)
        #pragma unroll
        for (int ni = 0; ni < 4; ++ni) acc[mi][ni] = (v4f){0.f, 0.f, 0.f, 0.f};
    for (int kt = 0; kt < 12; ++kt) {
        int k0 = kt * 64;
        #pragma unroll
        for (int c = 0; c < 4; ++c) {
            int rb = wid * 32 + c * 8;
            int r = rb + lrow;
            gload16((char*)As + rb * 128, A + (size_t)(m0 + r) * 768 + k0 + s * 8);
            gload16((char*)Bs + rb * 128, W + (size_t)(n0 + r) * 768 + k0 + s * 8);
        }
        __syncthreads();
        #pragma unroll
        for (int kk = 0; kk < 2; ++kk) {
            int kb2 = (kk * 32 + kg * 8) * 2;
            v8bf af[4], bfr[4];
            #pragma unroll
            for (int mi = 0; mi < 4; ++mi) {
                int rr = wm * 64 + mi * 16 + lr;
                af[mi] = *reinterpret_cast<const v8bf*>(reinterpret_cast<const char*>(As) + rr * 128 + (kb2 ^ ((rr & 7) << 4)));
            }
            #pragma unroll
            for (int ni = 0; ni < 4; ++ni) {
                int rr = wn * 64 + ni * 16 + lr;
                bfr[ni] = *reinterpret_cast<const v8bf*>(reinterpret_cast<const char*>(Bs) + rr * 128 + (kb2 ^ ((rr & 7) << 4)));
            }
            #pragma unroll
            for (int mi = 0; mi < 4; ++mi)
                #pragma unroll
                for (int ni = 0; ni < 4; ++ni)
                    acc[mi][ni] = __builtin_amdgcn_mfma_f32_16x16x32_bf16(af[mi], bfr[ni], acc[mi][ni], 0, 0, 0);
        }
        __syncthreads();
    }
}

// 5 projections: z = {qc(*0.125*log2e), kc, vc, qs(L2-normalized), vs} — coalesced epilogue
__global__ __launch_bounds__(256) void k_gemm_proj(
    const u16* __restrict__ fcb, const u16* __restrict__ fsb, const u16* __restrict__ Wt,
    u16* __restrict__ qc, u16* __restrict__ kc, u16* __restrict__ vc,
    u16* __restrict__ qs, u16* __restrict__ vs) {
    __shared__ __align__(16) u16 As[8192], Bs[8192];
    const u16* A; const u16* W; u16* O;
    switch (blockIdx.z) {
        case 0:  A = fcb; W = Wt;              O = qc; break;
        case 1:  A = fcb; W = Wt + 589824;     O = kc; break;
        case 2:  A = fcb; W = Wt + 2 * 589824; O = vc; break;
        case 3:  A = fsb; W = Wt + 3 * 589824; O = qs; break;
        default: A = fsb; W = Wt + 4 * 589824; O = vs; break;
    }
    int m0 = blockIdx.y * 128, n0 = blockIdx.x * 128;
    v4f acc[4][4];
    gemm_main(A, W, As, Bs, m0, n0, acc);
    const int lane = threadIdx.x & 63, wid = threadIdx.x >> 6;
    const int wm = wid >> 1, wn = wid & 1, lr = lane & 15, kg = lane >> 4;
    if (blockIdx.z == 0) {
        #pragma unroll
        for (int mi = 0; mi < 4; ++mi)
            #pragma unroll
            for (int ni = 0; ni < 4; ++ni)
                #pragma unroll
                for (int r = 0; r < 4; ++r) acc[mi][ni][r] *= 0.18033688f;
    } else if (blockIdx.z == 3) {
        #pragma unroll
        for (int mi = 0; mi < 4; ++mi)
            #pragma unroll
            for (int r = 0; r < 4; ++r) {
                float ss = 0.f;
                #pragma unroll
                for (int ni = 0; ni < 4; ++ni) ss += acc[mi][ni][r] * acc[mi][ni][r];
                ss += __shfl_xor(ss, 1); ss += __shfl_xor(ss, 2);
                ss += __shfl_xor(ss, 4); ss += __shfl_xor(ss, 8);
                float rs = rsqrtf(ss);
                #pragma unroll
                for (int ni = 0; ni < 4; ++ni) acc[mi][ni][r] *= rs;
            }
    }
    #pragma unroll
    for (int mi = 0; mi < 4; ++mi)
        #pragma unroll
        for (int ni = 0; ni < 4; ++ni)
            #pragma unroll
            for (int r = 0; r < 4; ++r) {
                int rowg = m0 + wm * 64 + mi * 16 + kg * 4 + r;
                int colg = n0 + wn * 64 + ni * 16 + lr;
                O[(size_t)rowg * 768 + colg] = f2bf(acc[mi][ni][r]);
            }
}

// final 2 projections + bias -> f32 d_out
__global__ __launch_bounds__(256) void k_gemm_out(
    const u16* __restrict__ ocb, const u16* __restrict__ osb, const u16* __restrict__ Wt,
    const float* __restrict__ bpc, const float* __restrict__ bps, float* __restrict__ out) {
    __shared__ __align__(16) u16 As[8192], Bs[8192];
    const u16* A; const u16* W; const float* bias; float* O;
    if (blockIdx.z == 0) { A = ocb; W = Wt + 5 * 589824; bias = bpc; O = out; }
    else                 { A = osb; W = Wt + 6 * 589824; bias = bps; O = out + 3145728; }
    int m0 = blockIdx.y * 128, n0 = blockIdx.x * 128;
    v4f acc[4][4];
    gemm_main(A, W, As, Bs, m0, n0, acc);
    const int lane = threadIdx.x & 63, wid = threadIdx.x >> 6;
    const int wm = wid >> 1, wn = wid & 1, lr = lane & 15, kg = lane >> 4;
    #pragma unroll
    for (int mi = 0; mi < 4; ++mi)
        #pragma unroll
        for (int ni = 0; ni < 4; ++ni)
            #pragma unroll
            for (int r = 0; r < 4; ++r) {
                int rowg = m0 + wm * 64 + mi * 16 + kg * 4 + r;
                int colg = n0 + wn * 64 + ni * 16 + lr;
                O[(size_t)rowg * 768 + colg] = acc[mi][ni][r] + bias[colg];
            }
}

// ---------------- V transpose: vT[(bh*64+d)*1024 + n] = v[(b*1024+n)*768 + h*64 + d] ----------------
__global__ __launch_bounds__(256) void k_transpose_v(
    const u16* __restrict__ vc, const u16* __restrict__ vs,
    u16* __restrict__ vcT, u16* __restrict__ vsT) {
    __shared__ u16 tile[64][65];
    const u16* src = blockIdx.z ? vs : vc;
    u16* dst = blockIdx.z ? vsT : vcT;
    int bh = blockIdx.y, b = bh / 12, h = bh % 12;
    int n0 = blockIdx.x * 64;
    int t = threadIdx.x;
    #pragma unroll
    for (int i = 0; i < 16; ++i) {
        int idx = i * 256 + t, n = idx >> 6, d = idx & 63;
        tile[n][d] = src[(size_t)(b * 1024 + n0 + n) * 768 + h * 64 + d];
    }
    __syncthreads();
    #pragma unroll
    for (int i = 0; i < 16; ++i) {
        int idx = i * 256 + t, d = idx >> 6, n = idx & 63;
        dst[(size_t)(bh * 64 + d) * 1024 + n0 + n] = tile[n][d];
    }
}

// ---------------- flash attention (round-7 proven 4-wave kernel + 4-bit swizzle) ----------------
// 32x32 swapped-QK, P in registers, 48KB LDS; K/Q2 single-buffered, Vc/Vs double-buffered.
// Swizzle upgrade: slot ^= ((row>>3)&1)<<2 (staged via source, read via ^((row>>3)&1)<<6)
// turns the 32-row ds_read 4-way bank conflict into free 2-way (rows r / r+8 now differ).
__global__ __launch_bounds__(256, 2) void k_attn(
    const u16* __restrict__ qc, const u16* __restrict__ kc, const u16* __restrict__ qsn,
    const u16* __restrict__ vcT, const u16* __restrict__ vsT,
    const float* __restrict__ gamma,
    u16* __restrict__ oc, u16* __restrict__ os) {
    __shared__ __align__(16) u16 SH[24576];    // 48KB: K[4096] Q2[4096] Vbuf[2][2][4096]
    u16* K_s8  = SH;
    u16* Q2_s8 = SH + 4096;
    u16* Vb    = SH + 8192;
    const int t = threadIdx.x, lane = t & 63, w = t >> 6;
    const int lq = lane & 31, hf = lane >> 5;
    const int qg = w >> 1, kvh = w & 1;
    const int lrow = lane >> 3, lslot = lane & 7;
    const int sslot = lslot ^ lrow;            // base pre-swizzled source slot

    // XCD-chunked swizzle (bijective: 768 = 8 * 96)
    int lin = blockIdx.y * 16 + blockIdx.x;
    int swz = (lin & 7) * 96 + (lin >> 3);
    const int qb = swz & 15, bh = swz >> 4;
    const int b = bh / 12, h = bh % 12;
    const float gam = gamma[h] * 1.44269504088896340736f;

    // per-wave staging source: wave w owns one array
    const u16* gb; size_t rstride, kmul;
    switch (w) {
        case 0:  gb = kc  + (size_t)b * 786432 + h * 64; rstride = 768;  kmul = 768; break;
        case 1:  gb = qsn + (size_t)b * 786432 + h * 64; rstride = 768;  kmul = 768; break;
        case 2:  gb = vcT + (size_t)bh * 65536;          rstride = 1024; kmul = 1;   break;
        default: gb = vsT + (size_t)bh * 65536;          rstride = 1024; kmul = 1;   break;
    }
    u16* fixdst = (w == 0) ? K_s8 : Q2_s8;     // staging dst for w<2 (single-buffered)

    // Q B-fragments in registers: lane holds col q = lq, k-slice = s*16 + hf*8
    const u16* qp1 = qc  + (size_t)(b * 1024 + qb * 64 + qg * 32 + lq) * 768 + h * 64 + hf * 8;
    const u16* qp2 = qsn + (size_t)(b * 1024 + qb * 64 + qg * 32 + lq) * 768 + h * 64 + hf * 8;
    v8bf qcB[4], qsB[4];
    #pragma unroll
    for (int s = 0; s < 4; ++s) {
        qcB[s] = *reinterpret_cast<const v8bf*>(qp1 + s * 16);
        qsB[s] = *reinterpret_cast<const v8bf*>(qp2 + s * 16);
    }

    f32x16 ocA[2], osA[2];
    #pragma unroll
    for (int dt = 0; dt < 2; ++dt) {
        #pragma unroll
        for (int r = 0; r < 16; ++r) { ocA[dt][r] = 0.f; osA[dt][r] = 0.f; }
    }
    float lsum = 0.f;

    // prologue: stage tile 0 (w0->K, w1->Q2, w2->Vc buf0, w3->Vs buf0)
    {
        char* ld = (w < 2) ? (char*)fixdst : (char*)(Vb + (w - 2) * 4096);
        #pragma unroll
        for (int c = 0; c < 8; ++c) {
            int r = c * 8 + lrow;
            int ss = sslot ^ ((c & 1) << 2);   // row>>3 parity bit into slot
            gload16(ld + c * 1024, gb + (size_t)r * rstride + ss * 8);
        }
    }
    wait_vm0();
    __builtin_amdgcn_s_barrier();

    int cur = 0;
    for (int tile = 0; tile < 16; ++tile) {
        // V(t+1) staging issues at top (w2/w3): hidden under the whole tile
        if (tile < 15 && w >= 2) {
            size_t kv1 = (size_t)(tile + 1) * 64;
            char* ld = (char*)(Vb + ((cur ^ 1) * 2 + (w - 2)) * 4096);
            #pragma unroll
            for (int c = 0; c < 8; ++c) {
                int r = c * 8 + lrow;
                int ss = sslot ^ ((c & 1) << 2);
                gload16(ld + c * 1024, gb + kv1 * kmul + (size_t)r * rstride + ss * 8);
            }
        }
        const char* K_s  = (const char*)K_s8;
        const char* Q2_s = (const char*)Q2_s8;
        const char* Vc_s = (const char*)(Vb + (cur * 2 + 0) * 4096);
        const char* Vs_s = (const char*)(Vb + (cur * 2 + 1) * 4096);

        // QK: S^T[32 kv][32 q], kv rows = this wave's half
        f32x16 ac, as;
        #pragma unroll
        for (int r = 0; r < 16; ++r) { ac[r] = 0.f; as[r] = 0.f; }
        const int rowA = kvh * 32 + lq;
        const int rswA = ((rowA & 7) << 4) ^ (((rowA >> 3) & 1) << 6);
        __builtin_amdgcn_s_setprio(1);
        #pragma unroll
        for (int s = 0; s < 4; ++s) {
            int colb = s * 32 + hf * 16;   // byte col: d = s*16 + hf*8
            int off = rowA * 128 + (colb ^ rswA);
            v8bf kf  = *reinterpret_cast<const v8bf*>(K_s + off);
            v8bf q2f = *reinterpret_cast<const v8bf*>(Q2_s + off);
            ac = __builtin_amdgcn_mfma_f32_32x32x16_bf16(kf,  qcB[s], ac, 0, 0, 0);
            as = __builtin_amdgcn_mfma_f32_32x32x16_bf16(q2f, qsB[s], as, 0, 0, 0);
        }
        __builtin_amdgcn_s_setprio(0);

        // barrier B: all waves done reading K/Q2(t) -> w0/w1 may overwrite
        __builtin_amdgcn_s_barrier();
        if (tile < 15 && w < 2) {
            size_t kv1 = (size_t)(tile + 1) * 64;
            #pragma unroll
            for (int c = 0; c < 8; ++c) {
                int r = c * 8 + lrow;
                int ss = sslot ^ ((c & 1) << 2);
                gload16((char*)fixdst + c * 1024, gb + kv1 * kmul + (size_t)r * rstride + ss * 8);
            }
        }

        // softmax (fixed-shift): p[r] for kv row (r&3)+8*(r>>2)+4*hf, q = lq
        float p[16];
        #pragma unroll
        for (int r = 0; r < 16; ++r)
            p[r] = __builtin_exp2f(fmaf(gam, as[r], ac[r]));
        lsum += ((p[0]+p[1])+(p[2]+p[3])) + ((p[4]+p[5])+(p[6]+p[7]))
              + ((p[8]+p[9])+(p[10]+p[11])) + ((p[12]+p[13])+(p[14]+p[15]));

        // pack P to bf16 A-fragment words (each = 2 consecutive kv)
        uint32_t A0 = pkbf(p[0], p[1]),  A1 = pkbf(p[2], p[3]);
        uint32_t A2 = pkbf(p[4], p[5]),  A3 = pkbf(p[6], p[7]);
        uint32_t A4 = pkbf(p[8], p[9]),  A5 = pkbf(p[10], p[11]);
        uint32_t A6 = pkbf(p[12], p[13]), A7 = pkbf(p[14], p[15]);
        // cross-half exchange, UNCONDITIONAL shfl payloads
        uint32_t pay0 = hf ? A0 : A2;
        uint32_t pay1 = hf ? A1 : A3;
        uint32_t rec0 = (uint32_t)__shfl_xor((int)pay0, 32);
        uint32_t rec1 = (uint32_t)__shfl_xor((int)pay1, 32);
        uint32_t w0 = hf ? rec0 : A0;
        uint32_t w1 = hf ? rec1 : A1;
        uint32_t w2 = hf ? A2 : rec0;
        uint32_t w3 = hf ? A3 : rec1;
        uint32_t pay2 = hf ? A4 : A6;
        uint32_t pay3 = hf ? A5 : A7;
        uint32_t rec2 = (uint32_t)__shfl_xor((int)pay2, 32);
        uint32_t rec3 = (uint32_t)__shfl_xor((int)pay3, 32);
        uint32_t w4 = hf ? rec2 : A4;
        uint32_t w5 = hf ? rec3 : A5;
        uint32_t w6 = hf ? A6 : rec2;
        uint32_t w7 = hf ? A7 : rec3;
        union { uint32_t u[4]; v8bf v; } pa0, pa1;
        pa0.u[0] = w0; pa0.u[1] = w1; pa0.u[2] = w2; pa0.u[3] = w3;
        pa1.u[0] = w4; pa1.u[1] = w5; pa1.u[2] = w6; pa1.u[3] = w7;

        // PV: O[32 q][32 d] per d-tile; A = P-frag, B = V-frag (col d = lq)
        __builtin_amdgcn_s_setprio(1);
        #pragma unroll
        for (int dt = 0; dt < 2; ++dt) {
            int rowV = dt * 32 + lq;
            int rswV = ((rowV & 7) << 4) ^ (((rowV >> 3) & 1) << 6);
            #pragma unroll
            for (int s = 0; s < 2; ++s) {
                int colb = kvh * 64 + s * 32 + hf * 16;  // byte col: kv = kvh*32+s*16+hf*8
                int off = rowV * 128 + (colb ^ rswV);
                v8bf vcf = *reinterpret_cast<const v8bf*>(Vc_s + off);
                v8bf vsf = *reinterpret_cast<const v8bf*>(Vs_s + off);
                v8bf ap = s ? pa1.v : pa0.v;
                ocA[dt] = __builtin_amdgcn_mfma_f32_32x32x16_bf16(ap, vcf, ocA[dt], 0, 0, 0);
                osA[dt] = __builtin_amdgcn_mfma_f32_32x32x16_bf16(ap, vsf, osA[dt], 0, 0, 0);
            }
        }
        __builtin_amdgcn_s_setprio(0);

        // wait own staging loads, then barrier A
        wait_vm0();
        __builtin_amdgcn_s_barrier();
        cur ^= 1;
    }

    // ---- epilogue: cross-kv-half reduction via LDS ----
    lsum += __shfl_xor(lsum, 32);
    float* red   = reinterpret_cast<float*>(SH);
    float* red_l = red;                  // [2 qg][32 q]
    float* red_o = red + 64;             // [2 qg][64 idx][64 lane]
    if (kvh == 1) {
        if (lane < 32) red_l[qg * 32 + lq] = lsum;
        #pragma unroll
        for (int st = 0; st < 2; ++st)
            #pragma unroll
            for (int dt = 0; dt < 2; ++dt)
                #pragma unroll
                for (int r = 0; r < 16; ++r) {
                    int idx = st * 32 + dt * 16 + r;
                    float v = st ? osA[dt][r] : ocA[dt][r];
                    red_o[(qg * 64 + idx) * 64 + lane] = v;
                }
    }
    __syncthreads();
    if (kvh == 0) {
        float ltot = lsum + red_l[qg * 32 + lq];
        float rl = 1.0f / ltot;
        if (lane < 32) red_l[qg * 32 + lq] = rl;
        #pragma unroll
        for (int st = 0; st < 2; ++st)
            #pragma unroll
            for (int dt = 0; dt < 2; ++dt)
                #pragma unroll
                for (int r = 0; r < 16; ++r) {
                    int rowq = (r & 3) + 8 * (r >> 2) + 4 * hf;
                    float rlv = red_l[qg * 32 + rowq];
                    int idx = st * 32 + dt * 16 + r;
                    float own = st ? osA[dt][r] : ocA[dt][r];
                    float v = (own + red_o[(qg * 64 + idx) * 64 + lane]) * rlv;
                    u16* dst = st ? os : oc;
                    dst[(size_t)(b * 1024 + qb * 64 + qg * 32 + rowq) * 768 + h * 64 + dt * 32 + lq] = f2bf(v);
                }
    }
}

extern "C" void kernel_launch(void* const* d_in, const int* in_sizes, int n_in,
                              void* d_out, int out_size, void* d_ws, size_t ws_size,
                              hipStream_t stream) {
    const float* fc    = (const float*)d_in[0];
    const float* fs    = (const float*)d_in[1];
    const float* Wqc   = (const float*)d_in[2];
    const float* Wqs   = (const float*)d_in[3];
    const float* Wkc   = (const float*)d_in[4];
    const float* Wvc   = (const float*)d_in[5];
    const float* Wvs   = (const float*)d_in[6];
    const float* gamma = (const float*)d_in[7];
    const float* Wpc   = (const float*)d_in[8];
    const float* bpc   = (const float*)d_in[9];
    const float* Wps   = (const float*)d_in[10];
    const float* bps   = (const float*)d_in[11];
    float* out = (float*)d_out;

    const size_t NT = 3145728;  // 4096*768 elements
    u16* ws  = (u16*)d_ws;
    u16* fcb = ws;
    u16* fsb = fcb + NT;
    u16* Wt  = fsb + NT;            // 7 * 589824
    u16* qc  = Wt + (size_t)7 * 589824;
    u16* kc  = qc + NT;
    u16* vc  = kc + NT;
    u16* qs  = vc + NT;
    u16* vs  = qs + NT;
    u16* vcT = vs + NT;
    u16* vsT = vcT + NT;
    u16* ocb = fcb;  // fcb/fsb dead after projections -> reuse for attention outputs
    u16* osb = fsb;

    k_prep<<<10176, 256, 0, stream>>>(fc, fs, fcb, fsb, Wqc, Wkc, Wvc, Wqs, Wvs, Wpc, Wps, Wt);
    k_gemm_proj<<<dim3(6, 32, 5), 256, 0, stream>>>(fcb, fsb, Wt, qc, kc, vc, qs, vs);
    k_transpose_v<<<dim3(16, 48, 2), 256, 0, stream>>>(vc, vs, vcT, vsT);
    k_attn<<<dim3(16, 48), 256, 0, stream>>>(qc, kc, qs, vcT, vsT, gamma, ocb, osb);
    k_gemm_out<<<dim3(6, 32, 2), 256, 0, stream>>>(ocb, osb, Wt, bpc, bps, out);
}